// Round 2
// baseline (308.329 us; speedup 1.0000x reference)
//
#include <hip/hip_runtime.h>

#define NHEADS 16
#define DIM 128
#define MQ 1024
#define LK 1024

typedef short short8 __attribute__((ext_vector_type(8)));
typedef float f32x16 __attribute__((ext_vector_type(16)));

// (1/sqrt(128)) * log2(e): fold softmax scale + exp2-domain into Q conversion
#define QSCALE_L2E 0.12751722f

// pack two floats -> two bf16 (round-to-nearest-even), self-contained
__device__ __forceinline__ unsigned pk2(float a, float b) {
  unsigned ua = __builtin_bit_cast(unsigned, a);
  unsigned ub = __builtin_bit_cast(unsigned, b);
  ua += 0x7fffu + ((ua >> 16) & 1u);
  ub += 0x7fffu + ((ub >> 16) & 1u);
  return (ua >> 16) | (ub & 0xffff0000u);
}
__device__ __forceinline__ short8 ld8(const unsigned short* p) {
  return __builtin_bit_cast(short8, *(const uint4*)p);
}

// One block: 128 queries of one (b,h); 4 waves x 32 queries; K-tiles of 64.
// S^T = K*Q^T via mfma_32x32x16_bf16 (lane owns one query -> cheap online softmax),
// O^T = V^T * P^T, P via LDS round-trip, V staged transposed.
__global__ __launch_bounds__(256, 2)
void SeqAttention_59579786330678_kernel(const float* __restrict__ Qg,
                                        const float* __restrict__ Kg,
                                        const float* __restrict__ Vg,
                                        const float* __restrict__ Sg,
                                        float* __restrict__ Og) {
  // LDS: Ks [64][136] bf16 (17408 B) | Vt [128][72] bf16 (18432 B) | Pb [4][32][72] bf16 (18432 B)
  // epilogue reuses front as float Otr[4][32][68] (34816 B)
  __shared__ __align__(16) unsigned char SM[54272];
  unsigned short* Ks = (unsigned short*)SM;
  unsigned short* Vt = (unsigned short*)(SM + 17408);
  unsigned short* Pb = (unsigned short*)(SM + 35840);

  const int tid = threadIdx.x;
  const int wid = tid >> 6;
  const int lane = tid & 63;
  const int lo = lane & 31;   // MFMA col -> this lane's query (within wave)
  const int hi = lane >> 5;   // MFMA k-half / row-offset bit

  const int bh = blockIdx.x >> 3;
  const int m0 = (blockIdx.x & 7) << 7;
  const float sv = Sg[bh & (NHEADS - 1)];
  // mask(n) = clamp((n - tval)/32, 0, 1); zero for n <= floor(tval) -> skip those tiles (exact)
  const float tval = 991.0f - sv * 1024.0f;
  int nf = (int)floorf(tval);
  nf = nf < 0 ? 0 : nf;
  const int tile0 = nf >> 6;

  // loop-invariant Q fragments (B-operand of K*Q^T), scale folded into bf16 convert
  short8 qf[8];
  {
    const float* qrow = Qg + ((size_t)bh * MQ + m0 + wid * 32 + lo) * DIM + hi * 8;
#pragma unroll
    for (int kc = 0; kc < 8; ++kc) {
      float4 x = *(const float4*)(qrow + kc * 16);
      float4 y = *(const float4*)(qrow + kc * 16 + 4);
      uint4 u;
      u.x = pk2(x.x * QSCALE_L2E, x.y * QSCALE_L2E);
      u.y = pk2(x.z * QSCALE_L2E, x.w * QSCALE_L2E);
      u.z = pk2(y.x * QSCALE_L2E, y.y * QSCALE_L2E);
      u.w = pk2(y.z * QSCALE_L2E, y.w * QSCALE_L2E);
      qf[kc] = __builtin_bit_cast(short8, u);
    }
  }

  f32x16 accO[4] = {};              // O^T accumulator: 4 d-blocks of 32
  float Mrun = -3.0e38f, lrun = 0.0f;
  const float hoff = (float)hi * 0.125f;   // 4*hi/32 row offset for mask

  const int vnp2 = (tid >> 3) * 2;  // V staging: key-pair base
  const int vdq = (tid & 7) * 4;    // V staging: d quad base
  const int kn = tid >> 4;          // K staging: row
  const int kc0 = (tid & 15) * 8;   // K staging: col base

  const float* Kbh = Kg + (size_t)bh * LK * DIM;
  const float* Vbh = Vg + (size_t)bh * LK * DIM;

  for (int it = tile0; it < 16; ++it) {
    const int n0 = it << 6;
    // ---- stage K tile: bf16, n-major, pad 136 ----
#pragma unroll
    for (int p = 0; p < 4; ++p) {
      const int n = kn + p * 16;
      const float* kp = Kbh + (size_t)(n0 + n) * DIM + kc0;
      float4 a = *(const float4*)kp;
      float4 b = *(const float4*)(kp + 4);
      uint4 u;
      u.x = pk2(a.x, a.y); u.y = pk2(a.z, a.w);
      u.z = pk2(b.x, b.y); u.w = pk2(b.z, b.w);
      *(uint4*)&Ks[n * 136 + kc0] = u;
    }
    // ---- stage V tile transposed: Vt[d][n], key-pairs packed in one u32 write ----
#pragma unroll
    for (int p = 0; p < 4; ++p) {
      const int d0 = p * 32 + vdq;
      const float* vp = Vbh + (size_t)(n0 + vnp2) * DIM + d0;
      float4 a = *(const float4*)vp;
      float4 b = *(const float4*)(vp + DIM);
      *(unsigned*)&Vt[(d0 + 0) * 72 + vnp2] = pk2(a.x, b.x);
      *(unsigned*)&Vt[(d0 + 1) * 72 + vnp2] = pk2(a.y, b.y);
      *(unsigned*)&Vt[(d0 + 2) * 72 + vnp2] = pk2(a.z, b.z);
      *(unsigned*)&Vt[(d0 + 3) * 72 + vnp2] = pk2(a.w, b.w);
    }
    __syncthreads();

    // ---- S^T = K * Q^T : rows n (0..63 in 2 blocks), cols m = lo ----
    f32x16 sa[2] = {};
#pragma unroll
    for (int kc = 0; kc < 8; ++kc) {
      short8 k0 = ld8(&Ks[lo * 136 + kc * 16 + hi * 8]);
      short8 k1 = ld8(&Ks[(32 + lo) * 136 + kc * 16 + hi * 8]);
      sa[0] = __builtin_amdgcn_mfma_f32_32x32x16_bf16(k0, qf[kc], sa[0], 0, 0, 0);
      sa[1] = __builtin_amdgcn_mfma_f32_32x32x16_bf16(k1, qf[kc], sa[1], 0, 0, 0);
    }

    // ---- online softmax over n for query m = lo (in-lane + one xor-32 shuffle) ----
    float rm = -3.0e38f;
#pragma unroll
    for (int r = 0; r < 16; ++r) rm = fmaxf(rm, fmaxf(sa[0][r], sa[1][r]));
    rm = fmaxf(rm, __shfl_xor(rm, 32));
    const float Mn = fmaxf(Mrun, rm);
    const float alpha = __builtin_amdgcn_exp2f(Mrun - Mn);
    Mrun = Mn;

    const bool fullmask = ((float)n0 >= tval + 32.0f);  // whole tile has mask==1
    const float b0 = ((float)n0 - tval) * 0.03125f + hoff;
    unsigned short* pbrow = Pb + wid * (32 * 72) + lo * 72;
    float rs = 0.0f;
#pragma unroll
    for (int nb = 0; nb < 2; ++nb) {
#pragma unroll
      for (int g = 0; g < 4; ++g) {
        float pv0, pv1, pv2, pv3;
#pragma unroll
        for (int i = 0; i < 4; ++i) {
          float e = __builtin_amdgcn_exp2f(sa[nb][g * 4 + i] - Mn);
          if (!fullmask) {
            float mv = b0 + (float)(i + 8 * g + 32 * nb) * 0.03125f;
            mv = __builtin_amdgcn_fmed3f(mv, 0.0f, 1.0f);
            e *= mv;
          }
          rs += e;
          if (i == 0) pv0 = e; else if (i == 1) pv1 = e; else if (i == 2) pv2 = e; else pv3 = e;
        }
        uint2 w;
        w.x = pk2(pv0, pv1);
        w.y = pk2(pv2, pv3);
        // n = i + 8g + 4hi + 32nb, row = query m = lo  (P stored m-major for PV B-frags)
        *(uint2*)(pbrow + nb * 32 + g * 8 + hi * 4) = w;
      }
    }
    rs += __shfl_xor(rs, 32);
    lrun = lrun * alpha + rs;
#pragma unroll
    for (int db = 0; db < 4; ++db)
#pragma unroll
      for (int r = 0; r < 16; ++r) accO[db][r] *= alpha;

    __syncthreads();  // Pb visibility (and uniform step)

    // ---- O^T += V^T * P^T ----
#pragma unroll
    for (int pc = 0; pc < 4; ++pc) {
      short8 pf = ld8(&Pb[wid * (32 * 72) + lo * 72 + pc * 16 + hi * 8]);
#pragma unroll
      for (int db = 0; db < 4; ++db) {
        short8 vf = ld8(&Vt[(db * 32 + lo) * 72 + pc * 16 + hi * 8]);
        accO[db] = __builtin_amdgcn_mfma_f32_32x32x16_bf16(vf, pf, accO[db], 0, 0, 0);
      }
    }
    __syncthreads();  // protect Ks/Vt for next iteration's staging
  }

  // ---- epilogue: /l, transpose O^T -> O via LDS (two d-halves), coalesced stores ----
  const float invl = 1.0f / lrun;
  float* Otr = (float*)SM + wid * (32 * 68);
  const size_t obase = ((size_t)bh * MQ + m0 + wid * 32) * DIM;
#pragma unroll
  for (int hf = 0; hf < 2; ++hf) {
    __syncthreads();
#pragma unroll
    for (int db = 0; db < 2; ++db) {
      const int adb = hf * 2 + db;
#pragma unroll
      for (int r = 0; r < 16; ++r) {
        const int dl = db * 32 + (r & 3) + 8 * (r >> 2) + 4 * hi;
        Otr[lo * 68 + dl] = accO[adb][r] * invl;
      }
    }
    __syncthreads();
    const int mr = lane >> 1;
    const int c0 = (lane & 1) * 32;
    const float* src = Otr + mr * 68 + c0;
    float* dst = Og + obase + (size_t)mr * DIM + hf * 64 + c0;
#pragma unroll
    for (int i = 0; i < 8; ++i)
      *(float4*)(dst + i * 4) = *(const float4*)(src + i * 4);
  }
}

extern "C" void kernel_launch(void* const* d_in, const int* in_sizes, int n_in,
                              void* d_out, int out_size, void* d_ws, size_t ws_size,
                              hipStream_t stream) {
  const float* Q = (const float*)d_in[0];
  const float* K = (const float*)d_in[1];
  const float* V = (const float*)d_in[2];
  const float* S = (const float*)d_in[3];
  float* O = (float*)d_out;
  dim3 grid(1024);   // 128 bh x 8 m-tiles
  dim3 block(256);   // 4 waves x 32 queries each
  SeqAttention_59579786330678_kernel<<<grid, block, 0, stream>>>(Q, K, V, S, O);
}